// Round 5
// baseline (45.188 us; speedup 1.0000x reference)
//
#include <hip/hip_runtime.h>
#include <hip/hip_bf16.h>

#define NE 9          // experts
#define NDIM 1024     // feature dim
#define BM 64         // M-tile
#define BN 128        // N-tile
#define BK 64         // K-step (floats)
#define NT (NDIM / BK)   // 16
#define MAX_SLOTS 80     // sum ceil(cnt_e/64) <= 72

typedef __attribute__((ext_vector_type(8))) short bf16x8;
typedef __attribute__((ext_vector_type(4))) float f32x4;

__device__ __forceinline__ unsigned pack2_bf16(float a, float b) {
    __hip_bfloat162 h = __float22bfloat162_rn(float2{a, b});
    return *reinterpret_cast<unsigned*>(&h);
}

// ---------------- bucket samples by expert + build M-tile slot table ----------------
__global__ __launch_bounds__(512)
void bucket_kernel(const int* __restrict__ sidx,
                   int* __restrict__ perm,
                   int* __restrict__ offsets,
                   int* __restrict__ slot_e,
                   int* __restrict__ slot_m0,
                   int* __restrict__ nslots,
                   int nB) {
    __shared__ int cnt[NE];
    __shared__ int cur[NE];
    int t = threadIdx.x;
    if (t < NE) cnt[t] = 0;
    __syncthreads();
    for (int i = t; i < nB; i += 512) atomicAdd(&cnt[sidx[i]], 1);
    __syncthreads();
    if (t == 0) {
        int run = 0, s = 0;
        for (int e = 0; e < NE; ++e) {
            cur[e] = run; offsets[e] = run;
            for (int m0 = 0; m0 < cnt[e]; m0 += BM) {
                slot_e[s] = e; slot_m0[s] = m0; ++s;
            }
            run += cnt[e];
        }
        offsets[NE] = run;
        *nslots = s;
    }
    __syncthreads();
    for (int i = t; i < nB; i += 512) {
        int p = atomicAdd(&cur[sidx[i]], 1);
        perm[p] = i;
    }
}

// ---------------- fully-fused f32 grouped GEMM -------------------------------------
// out[perm rows] = x @ W[e]^T + b[e].  256 threads = 4 waves (2M x 2N), wave 32x64.
// Both operands reg-staged from f32 (T14 issue-early/consume-late) + in-reg bf16 cvt
// + swizzled ds_write; ONE barrier per K-step, no vmcnt drain at barrier.
__global__ __launch_bounds__(256, 3)
void gemm_fused_kernel(const float* __restrict__ x,
                       const float* __restrict__ W,
                       const float* __restrict__ bias,
                       const int* __restrict__ perm,
                       const int* __restrict__ offsets,
                       const int* __restrict__ slot_e,
                       const int* __restrict__ slot_m0,
                       const int* __restrict__ nslots,
                       float* __restrict__ out) {
    // balanced contiguous slot->XCD partition (bijective)
    const int b    = blockIdx.x;
    const int xcd  = b & 7;
    const int j    = b >> 3;
    const int ns   = *nslots;
    const int q    = ns >> 3, r = ns & 7;
    const int mine = q + (xcd < r ? 1 : 0);
    const int ls   = j >> 3;
    if (ls >= mine) return;
    const int slot = xcd * q + (xcd < r ? xcd : r) + ls;
    const int n    = j & 7;

    const int e   = slot_e[slot];
    const int m0  = slot_m0[slot];
    const int off = offsets[e];
    const int cnt = offsets[e + 1] - off;
    const int n0  = n * BN;

    // ushort-indexed LDS: A bufs @ {0,4096}, B bufs @ {8192,16384}; 48 KB total
    __shared__ __align__(16) unsigned short lds[24576];

    const int t    = threadIdx.x;
    const int wave = t >> 6;
    const int lane = t & 63;
    const int fr   = lane & 15;
    const int fq   = lane >> 4;
    const int wr   = (wave >> 1) * 32;   // wave M-origin
    const int wc   = (wave & 1) * 64;    // wave N-origin
    const int xr   = fr & 7;             // read-side swizzle key

    // ---- staging map: 8 lanes cover one row's 64 f32 (each lane 8 f32 = 32 B) ----
    const int c8 = t & 7;        // col octet within K-block
    const int rg = t >> 3;       // row within 32-row group (0..31)
    const int wcol = (c8 ^ (rg & 7)) * 8;   // swizzled ushort col (rows rg+32k share rg&7)

    int ar0 = m0 + rg;      if (ar0 >= cnt) ar0 = cnt - 1;   // clamped pad rows;
    int ar1 = m0 + 32 + rg; if (ar1 >= cnt) ar1 = cnt - 1;   // masked at store
    const float* ap0 = x + (size_t)perm[off + ar0] * NDIM + c8 * 8;
    const float* ap1 = x + (size_t)perm[off + ar1] * NDIM + c8 * 8;
    const float* bp  = W + ((size_t)e * NDIM + n0 + rg) * NDIM + c8 * 8;

    float4 sa[4], sb[8];   // staged tile: A 2 rows x 2 float4, B 4 rows x 2 float4

#define LOADR(K0)                                                              \
    do {                                                                       \
        sa[0] = *(const float4*)(ap0 + (K0));                                  \
        sa[1] = *(const float4*)(ap0 + (K0) + 4);                              \
        sa[2] = *(const float4*)(ap1 + (K0));                                  \
        sa[3] = *(const float4*)(ap1 + (K0) + 4);                              \
        sb[0] = *(const float4*)(bp + (K0));                                   \
        sb[1] = *(const float4*)(bp + (K0) + 4);                               \
        sb[2] = *(const float4*)(bp + (size_t)32 * NDIM + (K0));               \
        sb[3] = *(const float4*)(bp + (size_t)32 * NDIM + (K0) + 4);           \
        sb[4] = *(const float4*)(bp + (size_t)64 * NDIM + (K0));               \
        sb[5] = *(const float4*)(bp + (size_t)64 * NDIM + (K0) + 4);           \
        sb[6] = *(const float4*)(bp + (size_t)96 * NDIM + (K0));               \
        sb[7] = *(const float4*)(bp + (size_t)96 * NDIM + (K0) + 4);           \
    } while (0)

#define PKW(DST, U, V)                                                         \
    do {                                                                       \
        uint4 o;                                                               \
        o.x = pack2_bf16((U).x, (U).y);                                        \
        o.y = pack2_bf16((U).z, (U).w);                                        \
        o.z = pack2_bf16((V).x, (V).y);                                        \
        o.w = pack2_bf16((V).z, (V).w);                                        \
        *reinterpret_cast<uint4*>(DST) = o;                                    \
    } while (0)

#define CVTW(BUF)                                                              \
    do {                                                                       \
        PKW(&lds[(BUF) * 4096 + rg * 64 + wcol], sa[0], sa[1]);                \
        PKW(&lds[(BUF) * 4096 + (32 + rg) * 64 + wcol], sa[2], sa[3]);         \
        PKW(&lds[8192 + (BUF) * 8192 + rg * 64 + wcol], sb[0], sb[1]);         \
        PKW(&lds[8192 + (BUF) * 8192 + (32 + rg) * 64 + wcol], sb[2], sb[3]);  \
        PKW(&lds[8192 + (BUF) * 8192 + (64 + rg) * 64 + wcol], sb[4], sb[5]);  \
        PKW(&lds[8192 + (BUF) * 8192 + (96 + rg) * 64 + wcol], sb[6], sb[7]);  \
    } while (0)

    f32x4 acc[2][4];
#pragma unroll
    for (int i = 0; i < 2; ++i)
#pragma unroll
        for (int k = 0; k < 4; ++k) acc[i][k] = (f32x4)(0.0f);

    // prologue: tile 0 staged to buf0; tile 1 loads in flight
    LOADR(0);
    CVTW(0);
    LOADR(BK);
    __syncthreads();

    for (int tt = 0; tt < NT; ++tt) {
        const int curb = tt & 1;

        // ---- compute on buf[curb] ----
#pragma unroll
        for (int kk = 0; kk < 2; ++kk) {
            const int cs = ((kk * 4 + fq) ^ xr) * 8;
            bf16x8 af[2], bfv[4];
#pragma unroll
            for (int mf = 0; mf < 2; ++mf)
                af[mf] = *reinterpret_cast<const bf16x8*>(
                    &lds[curb * 4096 + (wr + mf * 16 + fr) * 64 + cs]);
#pragma unroll
            for (int nf = 0; nf < 4; ++nf)
                bfv[nf] = *reinterpret_cast<const bf16x8*>(
                    &lds[8192 + curb * 8192 + (wc + nf * 16 + fr) * 64 + cs]);
            __builtin_amdgcn_s_setprio(1);
#pragma unroll
            for (int mf = 0; mf < 2; ++mf)
#pragma unroll
                for (int nf = 0; nf < 4; ++nf)
                    acc[mf][nf] = __builtin_amdgcn_mfma_f32_16x16x32_bf16(
                        af[mf], bfv[nf], acc[mf][nf], 0, 0, 0);
            __builtin_amdgcn_s_setprio(0);
        }

        if (tt + 1 < NT) {
            // write tile tt+1 (regs; auto-vmcnt waits only own loads, issued
            // a full compute phase ago). Writes target buf[curb^1]: last read
            // in iter tt-1, behind that iter's barrier -> no extra barrier.
            CVTW(curb ^ 1);
            // issue tile tt+2 loads into the freed staging regs; they fly
            // across barrier + compute(tt+1)
            if (tt + 2 < NT) LOADR((tt + 2) * BK);
            __syncthreads();   // ds_writes visible (lgkmcnt only; no vm drain)
        }
    }
#undef LOADR
#undef PKW
#undef CVTW

    // ---- epilogue: bias add + scatter store via perm ----
    float bl[4];
#pragma unroll
    for (int nf = 0; nf < 4; ++nf)
        bl[nf] = bias[e * NDIM + n0 + wc + nf * 16 + fr];

#pragma unroll
    for (int mf = 0; mf < 2; ++mf) {
#pragma unroll
        for (int jr = 0; jr < 4; ++jr) {
            int lm = wr + mf * 16 + fq * 4 + jr;
            if (m0 + lm < cnt) {
                int grow = perm[off + m0 + lm];
                float* orow = out + (size_t)grow * NDIM;
#pragma unroll
                for (int nf = 0; nf < 4; ++nf)
                    orow[n0 + wc + nf * 16 + fr] = acc[mf][nf][jr] + bl[nf];
            }
        }
    }
}

extern "C" void kernel_launch(void* const* d_in, const int* in_sizes, int n_in,
                              void* d_out, int out_size, void* d_ws, size_t ws_size,
                              hipStream_t stream) {
    const float* x    = (const float*)d_in[0];
    const float* W    = (const float*)d_in[1];
    const float* bias = (const float*)d_in[2];
    const int*   sidx = (const int*)d_in[3];
    float*       out  = (float*)d_out;

    const int nB = in_sizes[3];   // 4096

    char* wsb = (char*)d_ws;
    int* perm    = (int*)wsb;                         // [nB]
    int* offsets = (int*)(wsb + (size_t)nB * 4);      // [NE+1]
    int* slot_e  = offsets + NE + 1;                  // [MAX_SLOTS]
    int* slot_m0 = slot_e + MAX_SLOTS;                // [MAX_SLOTS]
    int* nslots  = slot_m0 + MAX_SLOTS;               // [1]

    bucket_kernel<<<1, 512, 0, stream>>>(sidx, perm, offsets, slot_e, slot_m0,
                                         nslots, nB);

    gemm_fused_kernel<<<MAX_SLOTS * 8, 256, 0, stream>>>(
        x, W, bias, perm, offsets, slot_e, slot_m0, nslots, out);
}

// Round 6
// 44.024 us; speedup vs baseline: 1.0265x; 1.0265x over previous
//
#include <hip/hip_runtime.h>
#include <hip/hip_bf16.h>

#define NE 9          // experts
#define NDIM 1024     // feature dim
#define BM 64         // M-tile
#define BN 128        // N-tile
#define BK 64         // K-step
#define NT (NDIM / BK)   // 16
#define MAX_SLOTS 80     // sum ceil(cnt_e/64) <= 72

typedef __attribute__((ext_vector_type(8))) short bf16x8;
typedef __attribute__((ext_vector_type(4))) float f32x4;

__device__ __forceinline__ unsigned pack2_bf16(float a, float b) {
    __hip_bfloat162 h = __float22bfloat162_rn(float2{a, b});
    return *reinterpret_cast<unsigned*>(&h);
}

__device__ __forceinline__ void gload_lds16(const void* g, void* l) {
    __builtin_amdgcn_global_load_lds(
        (const __attribute__((address_space(1))) unsigned int*)g,
        (__attribute__((address_space(3))) unsigned int*)l, 16, 0, 0);
}

// ---------------- fused: bucket (block 0) + W/x -> bf16 convert (blocks 1+) --------
__global__ __launch_bounds__(256)
void prep_kernel(const float* __restrict__ x, const float* __restrict__ W,
                 const int* __restrict__ sidx,
                 unsigned short* __restrict__ xb, unsigned short* __restrict__ Wb,
                 int* __restrict__ perm, int* __restrict__ offsets,
                 int* __restrict__ slot_e, int* __restrict__ slot_m0,
                 int* __restrict__ nslots, int nB) {
    if (blockIdx.x == 0) {
        __shared__ int cnt[NE];
        __shared__ int cur[NE];
        int t = threadIdx.x;
        if (t < NE) cnt[t] = 0;
        __syncthreads();
        for (int i = t; i < nB; i += 256) atomicAdd(&cnt[sidx[i]], 1);
        __syncthreads();
        if (t == 0) {
            int run = 0, s = 0;
            for (int e = 0; e < NE; ++e) {
                cur[e] = run; offsets[e] = run;
                for (int m0 = 0; m0 < cnt[e]; m0 += BM) {
                    slot_e[s] = e; slot_m0[s] = m0; ++s;
                }
                run += cnt[e];
            }
            offsets[NE] = run;
            *nslots = s;
        }
        __syncthreads();
        for (int i = t; i < nB; i += 256) {
            int p = atomicAdd(&cur[sidx[i]], 1);
            perm[p] = i;
        }
    } else {
        const int NW8 = NE * NDIM * (NDIM / 8);
        const int NX8 = nB * (NDIM / 8);
        const int tot = NW8 + NX8;
        const int stride = (gridDim.x - 1) * 256;
        for (int u = (blockIdx.x - 1) * 256 + threadIdx.x; u < tot; u += stride) {
            const float4* src;
            uint4* dst;
            if (u < NW8) {
                src = (const float4*)W + 2 * (size_t)u;
                dst = (uint4*)Wb + u;
            } else {
                size_t v = (size_t)(u - NW8);
                src = (const float4*)x + 2 * v;
                dst = (uint4*)xb + v;
            }
            float4 a = src[0], c = src[1];
            uint4 o;
            o.x = pack2_bf16(a.x, a.y);
            o.y = pack2_bf16(a.z, a.w);
            o.z = pack2_bf16(c.x, c.y);
            o.w = pack2_bf16(c.z, c.w);
            *dst = o;
        }
    }
}

// ---------------- bf16 grouped GEMM: 3-deep pipeline, counted vmcnt ---------------
// 256 threads = 4 waves (2M x 2N); wave tile 32x64. 3 LDS buffer pairs (72 KB);
// always 2 tiles (12 gload_lds) in flight; s_waitcnt vmcnt(6) + raw s_barrier.
__global__ __launch_bounds__(256, 2)
void gemm_bf16_kernel(const unsigned short* __restrict__ xb,
                      const unsigned short* __restrict__ Wb,
                      const float* __restrict__ bias,
                      const int* __restrict__ perm,
                      const int* __restrict__ offsets,
                      const int* __restrict__ slot_e,
                      const int* __restrict__ slot_m0,
                      const int* __restrict__ nslots,
                      float* __restrict__ out) {
    // balanced contiguous slot->XCD partition (bijective)
    const int b    = blockIdx.x;
    const int xcd  = b & 7;
    const int j    = b >> 3;
    const int ns   = *nslots;
    const int q    = ns >> 3, r = ns & 7;
    const int mine = q + (xcd < r ? 1 : 0);
    const int ls   = j >> 3;
    if (ls >= mine) return;
    const int slot = xcd * q + (xcd < r ? xcd : r) + ls;
    const int n    = j & 7;

    const int e   = slot_e[slot];
    const int m0  = slot_m0[slot];
    const int off = offsets[e];
    const int cnt = offsets[e + 1] - off;
    const int n0  = n * BN;

    // ushort-indexed LDS: A bufs @ {0,4096,8192}, B bufs @ 12288 + {0,8192,16384}
    __shared__ __align__(16) unsigned short lds[36864];   // 72 KB

    const int t    = threadIdx.x;
    const int wave = t >> 6;
    const int lane = t & 63;
    const int fr   = lane & 15;
    const int fq   = lane >> 4;
    const int wr   = (wave >> 1) * 32;   // wave M-origin
    const int wc   = (wave & 1) * 64;    // wave N-origin
    const int xr   = fr & 7;             // read-side swizzle key

    // staging: per-lane global source with PRE-SWIZZLED column; LDS dest linear.
    const int srow = t >> 3;                       // row within 32-row group
    const int scol = ((t & 7) ^ (srow & 7)) * 8;   // swizzled bf16 col in K-block
    int lm0 = m0 + srow;      if (lm0 >= cnt) lm0 = cnt - 1;   // clamp; masked at store
    int lm1 = m0 + 32 + srow; if (lm1 >= cnt) lm1 = cnt - 1;
    const unsigned short* asrc0 = xb + (size_t)perm[off + lm0] * NDIM + scol;
    const unsigned short* asrc1 = xb + (size_t)perm[off + lm1] * NDIM + scol;
    const unsigned short* bsrc  = Wb + ((size_t)e * NDIM + n0 + srow) * NDIM + scol;

#define STAGE(BUF, K0)                                                         \
    do {                                                                       \
        const int _ab = (BUF) * 4096;                                          \
        const int _bb = 12288 + (BUF) * 8192;                                  \
        gload_lds16(asrc0 + (K0), &lds[_ab + wave * 512]);                     \
        gload_lds16(asrc1 + (K0), &lds[_ab + 2048 + wave * 512]);              \
        _Pragma("unroll")                                                      \
        for (int i = 0; i < 4; ++i)                                            \
            gload_lds16(bsrc + (size_t)i * 32 * NDIM + (K0),                   \
                        &lds[_bb + i * 2048 + wave * 512]);                    \
    } while (0)

    f32x4 acc[2][4];
#pragma unroll
    for (int i = 0; i < 2; ++i)
#pragma unroll
        for (int k = 0; k < 4; ++k) acc[i][k] = (f32x4)(0.0f);

    // prologue: tiles 0 and 1 in flight (12 loads); wait oldest 6 -> buf0 ready
    STAGE(0, 0);
    STAGE(1, BK);
    asm volatile("s_waitcnt vmcnt(6)" ::: "memory");
    __builtin_amdgcn_s_barrier();

    int cur = 0;
#pragma unroll
    for (int tt = 0; tt < NT; ++tt) {
        // issue tile tt+2 into buf[(cur+2)%3] (last read at iter tt-1; all waves
        // past it via the barrier that ended iter tt-1)
        if (tt + 2 < NT) {
            int sb = cur + 2; if (sb >= 3) sb -= 3;
            STAGE(sb, (tt + 2) * BK);
        }

        const int abase = cur * 4096;
        const int bbase = 12288 + cur * 8192;
#pragma unroll
        for (int kk = 0; kk < 2; ++kk) {
            const int cs = ((kk * 4 + fq) ^ xr) * 8;
            bf16x8 af[2], bfv[4];
#pragma unroll
            for (int mf = 0; mf < 2; ++mf)
                af[mf] = *reinterpret_cast<const bf16x8*>(
                    &lds[abase + (wr + mf * 16 + fr) * 64 + cs]);
#pragma unroll
            for (int nf = 0; nf < 4; ++nf)
                bfv[nf] = *reinterpret_cast<const bf16x8*>(
                    &lds[bbase + (wc + nf * 16 + fr) * 64 + cs]);
#pragma unroll
            for (int mf = 0; mf < 2; ++mf)
#pragma unroll
                for (int nf = 0; nf < 4; ++nf)
                    acc[mf][nf] = __builtin_amdgcn_mfma_f32_16x16x32_bf16(
                        af[mf], bfv[nf], acc[mf][nf], 0, 0, 0);
        }

        if (tt + 1 < NT) {
            // counted wait: 12 outstanding -> <=6 means tile tt+1's loads done.
            // Tail (tt==NT-2): only 6 outstanding -> full drain.
            if (tt + 2 < NT)
                asm volatile("s_waitcnt vmcnt(6)" ::: "memory");
            else
                asm volatile("s_waitcnt vmcnt(0)" ::: "memory");
            __builtin_amdgcn_s_barrier();
        }
        cur = (cur + 1 < 3) ? cur + 1 : 0;
    }
#undef STAGE

    // ---- epilogue: bias add + scatter store via perm ----
    float bl[4];
#pragma unroll
    for (int nf = 0; nf < 4; ++nf)
        bl[nf] = bias[e * NDIM + n0 + wc + nf * 16 + fr];

#pragma unroll
    for (int mf = 0; mf < 2; ++mf) {
#pragma unroll
        for (int jr = 0; jr < 4; ++jr) {
            int lm = wr + mf * 16 + fq * 4 + jr;
            if (m0 + lm < cnt) {
                int grow = perm[off + m0 + lm];
                float* orow = out + (size_t)grow * NDIM;
#pragma unroll
                for (int nf = 0; nf < 4; ++nf)
                    orow[n0 + wc + nf * 16 + fr] = acc[mf][nf][jr] + bl[nf];
            }
        }
    }
}

// ---------------- tiny correct fallback (never expected to run) -------------------
__global__ void naive_kernel(const float* __restrict__ x, const float* __restrict__ W,
                             const float* __restrict__ bias,
                             const int* __restrict__ sidx, float* __restrict__ out,
                             int nB) {
    int i = blockIdx.x;              // sample
    int c = threadIdx.x + (blockIdx.y << 8);   // output col
    if (i >= nB || c >= NDIM) return;
    int e = sidx[i];
    const float* w = W + ((size_t)e * NDIM + c) * NDIM;
    const float* xr = x + (size_t)i * NDIM;
    float s = bias[e * NDIM + c];
    for (int k = 0; k < NDIM; ++k) s += xr[k] * w[k];
    out[(size_t)i * NDIM + c] = s;
}

extern "C" void kernel_launch(void* const* d_in, const int* in_sizes, int n_in,
                              void* d_out, int out_size, void* d_ws, size_t ws_size,
                              hipStream_t stream) {
    const float* x    = (const float*)d_in[0];
    const float* W    = (const float*)d_in[1];
    const float* bias = (const float*)d_in[2];
    const int*   sidx = (const int*)d_in[3];
    float*       out  = (float*)d_out;

    const int nB = in_sizes[3];   // 4096

    char* wsb = (char*)d_ws;
    size_t p_off   = (size_t)nB * 4;
    size_t p_slote = p_off + 64;
    size_t p_slotm = p_slote + MAX_SLOTS * 4;
    size_t p_nslot = p_slotm + MAX_SLOTS * 4;
    size_t p_xb    = ((p_nslot + 4 + 511) / 512) * 512;
    size_t p_wb    = p_xb + (size_t)nB * NDIM * 2;
    size_t need    = p_wb + (size_t)NE * NDIM * NDIM * 2;

    if (ws_size < need) {
        dim3 g(nB, NDIM / 256);
        naive_kernel<<<g, 256, 0, stream>>>(x, W, bias, sidx, out, nB);
        return;
    }

    int* perm    = (int*)(wsb + 0);
    int* offsets = (int*)(wsb + p_off);
    int* slot_e  = (int*)(wsb + p_slote);
    int* slot_m0 = (int*)(wsb + p_slotm);
    int* nslots  = (int*)(wsb + p_nslot);
    unsigned short* xb = (unsigned short*)(wsb + p_xb);
    unsigned short* Wb = (unsigned short*)(wsb + p_wb);

    prep_kernel<<<1024, 256, 0, stream>>>(x, W, sidx, xb, Wb, perm, offsets,
                                          slot_e, slot_m0, nslots, nB);

    gemm_bf16_kernel<<<MAX_SLOTS * 8, 256, 0, stream>>>(
        xb, Wb, bias, perm, offsets, slot_e, slot_m0, nslots, out);
}